// Round 15
// baseline (683.805 us; speedup 1.0000x reference)
//
#include <hip/hip_runtime.h>
#include <hip/hip_bf16.h>
#include <math.h>

#define K_CODES 8192
#define D_DIM   512
#define N_ROWS  16384
#define DECAYF  0.99f
#define OMDF    0.01f
#define COMMIT  0.25f
#define EPSV    1e-5f

// output offsets (in floats), reference return order:
// z_q_st (8*2048*512), loss (1), indices (8*2048), new_embedding (8192*512),
// ema_cs (8192), ema_es (8192*512)
#define OUT0_OFF 0ull
#define OUT1_OFF 8388608ull
#define OUT2_OFF 8388609ull
#define OUT3_OFF 8404993ull
#define OUT4_OFF 12599297ull
#define OUT5_OFF 12607489ull

#define BM 128
#define BN 256
#define NCB (K_CODES / BN)   // 32 colblocks
#define NRB (N_ROWS / BM)    // 128 rowblocks

typedef _Float16 f16x8 __attribute__((ext_vector_type(8)));
typedef _Float16 f16x4 __attribute__((ext_vector_type(4)));
typedef float    f32x4 __attribute__((ext_vector_type(4)));
typedef unsigned short u16;

#define GLOAD16(srcp, dstp) __builtin_amdgcn_global_load_lds( \
    (const __attribute__((address_space(1))) unsigned int*)(const void*)(srcp), \
    (__attribute__((address_space(3))) unsigned int*)(void*)(dstp), 16, 0, 0)

// ---------------- prep: pack + numpy norms + hi/lo norms + zeroing ----------------
// pack layout (16B granules): pack[((pb*16+c)*2+plane)*8192 + (g*256+r)*8 + e]
__device__ __forceinline__ void pack_tile(const float* __restrict__ src,
                                          u16* __restrict__ dst, float scale,
                                          int pb, int t, int tid,
                                          u16 (*simg)[1024][8]) {
    const float4* base = (const float4*)(src + ((size_t)pb * 256) * D_DIM + t * 32);
#pragma unroll
    for (int i = 0; i < 8; i++) {
        int f = tid + i * 256;
        int r = f >> 3, c = f & 7;
        float4 v = base[(size_t)r * 128 + c];
        float s0 = v.x * scale, s1 = v.y * scale, s2 = v.z * scale, s3 = v.w * scale;
        _Float16 h0 = (_Float16)s0, h1 = (_Float16)s1, h2 = (_Float16)s2, h3 = (_Float16)s3;
        f16x4 hv = {h0, h1, h2, h3};
        f16x4 lv = {(_Float16)(s0 - (float)h0), (_Float16)(s1 - (float)h1),
                    (_Float16)(s2 - (float)h2), (_Float16)(s3 - (float)h3)};
        int slot = (c >> 1) * 256 + r;
        int half = (c & 1) * 4;
        *(f16x4*)&simg[0][slot][half] = hv;
        *(f16x4*)&simg[1][slot][half] = lv;
    }
    __syncthreads();
    const u16* flat = &simg[0][0][0];
    u16* gout = dst + ((size_t)pb * 16 + t) * 2 * 8192;
#pragma unroll
    for (int i = 0; i < 8; i++) {
        int g = tid + i * 256;
        *(f16x8*)(gout + (size_t)g * 8) = *(const f16x8*)(flat + (size_t)g * 8);
    }
}

// numpy pairwise(512) exact sum of squares (8 rows / 256-thread block)
__device__ __forceinline__ void norms8(const float* __restrict__ src,
                                       float* __restrict__ dst, int rowbase, int tid) {
    int lane = tid & 63;
    int wave = tid >> 6;
    int half = lane >> 5;
    int l32  = lane & 31;
    int row  = rowbase + wave * 2 + half;
    int j    = l32 & 7;
    int blk  = l32 >> 3;
    const float* p = src + (size_t)row * D_DIM + blk * 128 + j;
    float x0 = p[0];
    float r = __fmul_rn(x0, x0);
#pragma unroll
    for (int i = 1; i < 16; i++) {
        float x = p[i * 8];
        r = __fadd_rn(r, __fmul_rn(x, x));
    }
    float s1 = __fadd_rn(r,  __shfl_xor(r, 1, 64));
    float s2 = __fadd_rn(s1, __shfl_xor(s1, 2, 64));
    float s4 = __fadd_rn(s2, __shfl_xor(s2, 4, 64));
    float t1 = __fadd_rn(s4, __shfl_xor(s4, 8, 64));
    float t2 = __fadd_rn(t1, __shfl_xor(t1, 16, 64));
    if (l32 == 0) dst[row] = t2;
}

// hi/lo split norms: 8 rows / block, 32 lanes per row
__device__ __forceinline__ void hlnorms8(const float* __restrict__ src, float scale,
                                         int rowbase, int tid,
                                         float* __restrict__ h2out, float* __restrict__ l2out,
                                         unsigned* __restrict__ mehbits, unsigned* __restrict__ melbits,
                                         int do_max) {
    int sub = tid >> 5, l32 = tid & 31;
    int row = rowbase + sub;
    const float4* p = (const float4*)(src + (size_t)row * D_DIM);
    float hs = 0.f, ls = 0.f;
#pragma unroll
    for (int i = 0; i < 4; i++) {
        float4 v = p[l32 + i * 32];
        float c[4] = {v.x, v.y, v.z, v.w};
#pragma unroll
        for (int q = 0; q < 4; q++) {
            float s = c[q] * scale;
            float hf = (float)(_Float16)s;
            float lf = s - hf;
            hs += hf * hf;
            ls += lf * lf;
        }
    }
#pragma unroll
    for (int off = 1; off <= 16; off <<= 1) {
        hs += __shfl_xor(hs, off, 64);
        ls += __shfl_xor(ls, off, 64);
    }
    if (l32 == 0) {
        if (do_max) {
            atomicMax(mehbits, __float_as_uint(sqrtf(hs) * 1.001f));
            atomicMax(melbits, __float_as_uint(sqrtf(ls) * 1.001f));
        } else {
            h2out[row] = hs;
            l2out[row] = ls;
        }
    }
}

__global__ void prep_kernel(const float* __restrict__ z, const float* __restrict__ E,
                            u16* __restrict__ zpack, u16* __restrict__ epack,
                            float* __restrict__ z2, float* __restrict__ e2,
                            float* __restrict__ nzh2, float* __restrict__ nzl2,
                            unsigned* __restrict__ mehbits, unsigned* __restrict__ melbits,
                            int* __restrict__ cnt, float* __restrict__ loss) {
    __shared__ __align__(16) u16 simg[2][1024][8];
    int bid = blockIdx.x;
    int tid = threadIdx.x;
    if (bid < 1024) {
        pack_tile(z, zpack, 1.0f, bid >> 4, bid & 15, tid, simg);
    } else if (bid < 1536) {
        int b = bid - 1024;
        pack_tile(E, epack, 4096.0f, b >> 4, b & 15, tid, simg);
    } else if (bid < 3584) {
        norms8(z, z2, (bid - 1536) * 8, tid);
    } else if (bid < 4608) {
        norms8(E, e2, (bid - 3584) * 8, tid);
    } else if (bid < 6656) {
        hlnorms8(z, 1.0f, (bid - 4608) * 8, tid, nzh2, nzl2, 0, 0, 0);
    } else if (bid < 7680) {
        hlnorms8(E, 4096.0f, (bid - 6656) * 8, tid, 0, 0, mehbits, melbits, 1);
    } else {
#pragma unroll
        for (int i = 0; i < 32; i++) cnt[tid + i * 256] = 0;
        if (tid == 0) loss[0] = 0.f;
    }
}

// ---------------- phase 1: hi-only est GEMM, BK=64, per-(row,cb) min ----------------
__global__ __launch_bounds__(512, 4) void est_mfma_kernel(
    const u16* __restrict__ zpack, const u16* __restrict__ epack,
    const float* __restrict__ e2, const float* __restrict__ z2,
    float* __restrict__ pvest)
{
    __shared__ __align__(16) u16 ldsA[2][512][8];    // [k32][g*128+r][8]  16 KB (hi only)
    __shared__ __align__(16) u16 ldsB[2][1024][8];   // [k32][g*256+rc][8] 32 KB (hi only)

    int bid = blockIdx.x;
    int xcd = bid & 7, sub = bid >> 3;
    int rb  = sub >> 2;
    int cb  = xcd * 4 + (sub & 3);
    int row0 = rb * BM, col0 = cb * BN;
    int pb   = rb >> 1, phalf = rb & 1;

    int tid = threadIdx.x;
    int l   = tid & 63;
    int w   = tid >> 6;
    int mw  = w >> 2, nw = w & 3;
    int lg  = l >> 4;
    int l16 = l & 15;

    f32x4 acc[4][4];
#pragma unroll
    for (int m = 0; m < 4; m++)
#pragma unroll
        for (int n = 0; n < 4; n++)
            acc[m][n] = (f32x4){0.f, 0.f, 0.f, 0.f};

    for (int t = 0; t < 8; t++) {        // BK=64: pack-chunks 2t, 2t+1, hi planes
        __syncthreads();
        const u16* zb = zpack + (((size_t)pb * 16 + 2 * t) * 2) * 8192;
        const u16* eb = epack + (((size_t)cb * 16 + 2 * t) * 2) * 8192;
#pragma unroll
        for (int i = 0; i < 2; i++) {    // A-hi: 1024 granules
            int idx = tid + i * 512;
            int c = idx >> 9, rem = idx & 511;
            int g = rem >> 7, r = rem & 127;
            GLOAD16(zb + (size_t)c * 16384 + ((size_t)g * 256 + phalf * 128 + r) * 8,
                    &ldsA[c][rem][0]);
        }
#pragma unroll
        for (int i = 0; i < 4; i++) {    // B-hi: 2048 granules
            int idx = tid + i * 512;
            int c = idx >> 10, rem = idx & 1023;
            GLOAD16(eb + (size_t)c * 16384 + (size_t)rem * 8, &ldsB[c][rem][0]);
        }
        __syncthreads();
#pragma unroll
        for (int k32 = 0; k32 < 2; k32++) {
            f16x8 bh[4];
#pragma unroll
            for (int n = 0; n < 4; n++)
                bh[n] = *(const f16x8*)&ldsB[k32][lg * 256 + nw * 64 + n * 16 + l16][0];
#pragma unroll
            for (int m = 0; m < 4; m++) {
                f16x8 ah = *(const f16x8*)&ldsA[k32][lg * 128 + mw * 64 + m * 16 + l16][0];
#pragma unroll
                for (int n = 0; n < 4; n++)
                    acc[m][n] = __builtin_amdgcn_mfma_f32_16x16x32_f16(ah, bh[n], acc[m][n], 0, 0, 0);
            }
        }
    }

    const float nscale = -0.00048828125f;
    float e2c[4];
#pragma unroll
    for (int n = 0; n < 4; n++) e2c[n] = e2[col0 + nw * 64 + n * 16 + l16];

    __syncthreads();
    float* redv = (float*)&ldsA[0][0][0];   // [128][4]
#pragma unroll
    for (int m = 0; m < 4; m++) {
#pragma unroll
        for (int r = 0; r < 4; r++) {
            int rl = mw * 64 + m * 16 + lg * 4 + r;
            float z2v = z2[row0 + rl];
            float bv = 1e30f;
#pragma unroll
            for (int n = 0; n < 4; n++) {
                float v = (z2v + acc[m][n][r] * nscale) + e2c[n];
                bv = fminf(bv, v);
            }
#pragma unroll
            for (int s = 1; s < 16; s <<= 1)
                bv = fminf(bv, __shfl_xor(bv, s, 64));
            if (l16 == r) redv[rl * 4 + nw] = bv;
        }
    }
    __syncthreads();
    if (tid < BM) {
        float bv = redv[tid * 4];
#pragma unroll
        for (int q = 1; q < 4; q++) bv = fminf(bv, redv[tid * 4 + q]);
        pvest[(size_t)cb * N_ROWS + row0 + tid] = bv;
    }
}

// ---------------- flag: per-row margin test -> per-cb row lists ----------------
__global__ void flag_kernel(const float* __restrict__ pvest,
                            const float* __restrict__ nzh2, const float* __restrict__ nzl2,
                            const unsigned* __restrict__ mehbits, const unsigned* __restrict__ melbits,
                            int* __restrict__ cnt2, int* __restrict__ cbrows) {
    int row = blockIdx.x * 256 + threadIdx.x;
    float m = 1e30f;
    for (int cb = 0; cb < NCB; cb++)
        m = fminf(m, pvest[(size_t)cb * N_ROWS + row]);
    float MEH = __uint_as_float(mehbits[0]);
    float MEL = __uint_as_float(melbits[0]);
    float nzh = sqrtf(nzh2[row]) * 1.001f;
    float nzl = sqrtf(nzl2[row]) * 1.001f;
    // |est - exact| <= 2^-11*(nzh*MEL + nzl*MEH) + fp32 rounding wobble
    float margin = 3.0f * 4.8828125e-4f * (nzh * MEL + nzl * MEH) + 1e-3f;
    float thr = m + margin;
    for (int cb = 0; cb < NCB; cb++) {
        if (pvest[(size_t)cb * N_ROWS + row] <= thr) {
            int slot = atomicAdd(&cnt2[cb], 1);
            cbrows[cb * N_ROWS + slot] = row;
        }
    }
}

// ---------------- phase 2: exact 3-product refine on flagged (row,cb) ----------------
// MFMA order identical to the validated r14 kernel -> bit-identical distances.
__global__ __launch_bounds__(512, 4) void refine_mfma_kernel(
    const u16* __restrict__ zpack, const u16* __restrict__ epack,
    const float* __restrict__ e2, const float* __restrict__ z2,
    const int* __restrict__ cnt2, const int* __restrict__ cbrows,
    float* __restrict__ pv2, int* __restrict__ pi2)
{
    __shared__ __align__(16) u16 ldsA[2][512][8];    // [plane][g*128+r][8]  16 KB
    __shared__ __align__(16) u16 ldsB[2][1024][8];   // [plane][g*256+rc][8] 32 KB
    __shared__ int rowsLds[128];

    int cb = blockIdx.x & 31, tile = blockIdx.x >> 5;
    int count = cnt2[cb];
    if (tile * 128 >= count) return;

    int tid = threadIdx.x;
    if (tid < 128) {
        int gi = tile * 128 + tid;
        rowsLds[tid] = cbrows[cb * N_ROWS + (gi < count ? gi : count - 1)];
    }
    __syncthreads();

    int col0 = cb * BN;
    int l   = tid & 63;
    int w   = tid >> 6;
    int mw  = w >> 2, nw = w & 3;
    int lg  = l >> 4;
    int l16 = l & 15;

    f32x4 acc[4][4];
#pragma unroll
    for (int m = 0; m < 4; m++)
#pragma unroll
        for (int n = 0; n < 4; n++)
            acc[m][n] = (f32x4){0.f, 0.f, 0.f, 0.f};

    for (int t = 0; t < 16; t++) {
        __syncthreads();
#pragma unroll
        for (int i = 0; i < 2; i++) {    // A hi+lo with row indirection (per-lane src)
            int idx = tid + i * 512;
            int p = idx >> 9, rem = idx & 511;
            int g = rem >> 7, r = rem & 127;
            int R = rowsLds[r];
            GLOAD16(zpack + ((((size_t)(R >> 8) * 16 + t) * 2 + p)) * 8192
                          + ((size_t)g * 256 + (R & 255)) * 8,
                    &ldsA[p][rem][0]);
        }
        const u16* eb = epack + (((size_t)cb * 16 + t) * 2) * 8192;
#pragma unroll
        for (int i = 0; i < 2; i++) {
            int slot = tid + i * 512;
            GLOAD16(eb + (size_t)slot * 8,        &ldsB[0][slot][0]);
            GLOAD16(eb + 8192 + (size_t)slot * 8, &ldsB[1][slot][0]);
        }
        __syncthreads();

        f16x8 bh[4], bl[4];
#pragma unroll
        for (int n = 0; n < 4; n++) {
            int s = lg * 256 + nw * 64 + n * 16 + l16;
            bh[n] = *(const f16x8*)&ldsB[0][s][0];
            bl[n] = *(const f16x8*)&ldsB[1][s][0];
        }
#pragma unroll
        for (int m = 0; m < 4; m++) {
            int s = lg * 128 + mw * 64 + m * 16 + l16;
            f16x8 ah = *(const f16x8*)&ldsA[0][s][0];
            f16x8 al = *(const f16x8*)&ldsA[1][s][0];
#pragma unroll
            for (int n = 0; n < 4; n++)
                acc[m][n] = __builtin_amdgcn_mfma_f32_16x16x32_f16(ah, bh[n], acc[m][n], 0, 0, 0);
#pragma unroll
            for (int n = 0; n < 4; n++)
                acc[m][n] = __builtin_amdgcn_mfma_f32_16x16x32_f16(ah, bl[n], acc[m][n], 0, 0, 0);
#pragma unroll
            for (int n = 0; n < 4; n++)
                acc[m][n] = __builtin_amdgcn_mfma_f32_16x16x32_f16(al, bh[n], acc[m][n], 0, 0, 0);
        }
    }

    const float nscale = -0.00048828125f;
    float e2c[4];
#pragma unroll
    for (int n = 0; n < 4; n++) e2c[n] = e2[col0 + nw * 64 + n * 16 + l16];

    __syncthreads();
    float* redv = (float*)&ldsA[0][0][0];   // [128][4]
    int*   redi = (int*)&ldsB[0][0][0];     // [128][4]
#pragma unroll
    for (int m = 0; m < 4; m++) {
#pragma unroll
        for (int r = 0; r < 4; r++) {
            int rl = mw * 64 + m * 16 + lg * 4 + r;
            float z2v = z2[rowsLds[rl]];
            float bv = 1e30f; int bc = 0x7fffffff;
#pragma unroll
            for (int n = 0; n < 4; n++) {
                int code = col0 + nw * 64 + n * 16 + l16;
                float v = __fadd_rn(__fadd_rn(z2v, __fmul_rn(acc[m][n][r], nscale)), e2c[n]);
                if (v < bv) { bv = v; bc = code; }
            }
#pragma unroll
            for (int s = 1; s < 16; s <<= 1) {
                float ov = __shfl_xor(bv, s, 64);
                int   oc = __shfl_xor(bc, s, 64);
                if (ov < bv || (ov == bv && oc < bc)) { bv = ov; bc = oc; }
            }
            if (l16 == r) {
                redv[rl * 4 + nw] = bv;
                redi[rl * 4 + nw] = bc;
            }
        }
    }
    __syncthreads();
    if (tid < 128 && tile * 128 + tid < count) {
        float bv = redv[tid * 4]; int bc = redi[tid * 4];
#pragma unroll
        for (int q = 1; q < 4; q++) {
            float v = redv[tid * 4 + q]; int c = redi[tid * 4 + q];
            if (v < bv || (v == bv && c < bc)) { bv = v; bc = c; }
        }
        int R = rowsLds[tid];
        pv2[(size_t)cb * N_ROWS + R] = bv;
        pi2[(size_t)cb * N_ROWS + R] = bc;
    }
}

// ---------------- fused: combine flagged exact partials + count + gather + loss ----
__global__ void combine_gather_kernel(const float* __restrict__ pv, const int* __restrict__ pi,
                                      const float* __restrict__ z, const float* __restrict__ E,
                                      int* __restrict__ idx_out, float* __restrict__ out2,
                                      int* __restrict__ cnt, float* __restrict__ out0,
                                      float* __restrict__ loss_acc) {
    int row = blockIdx.x;
    int t = threadIdx.x;   // 128
    __shared__ int ksh;
    if (t < 32) {
        float bv = pv[(size_t)t * N_ROWS + row];
        int   bc = pi[(size_t)t * N_ROWS + row];
#pragma unroll
        for (int s = 1; s < 32; s <<= 1) {
            float ov = __shfl_xor(bv, s, 64);
            int   oc = __shfl_xor(bc, s, 64);
            if (ov < bv || (ov == bv && oc < bc)) { bv = ov; bc = oc; }
        }
        if (t == 0) {
            idx_out[row] = bc;
            out2[row] = (float)bc;
            atomicAdd(&cnt[bc], 1);
            ksh = bc;
        }
    }
    __syncthreads();
    int k = ksh;
    int d = t * 4;
    float4 zv = *(const float4*)(z + (size_t)row * D_DIM + d);
    float4 qv = *(const float4*)(E + (size_t)k * D_DIM + d);
    float4 o;
    o.x = __fadd_rn(zv.x, __fsub_rn(qv.x, zv.x));
    o.y = __fadd_rn(zv.y, __fsub_rn(qv.y, zv.y));
    o.z = __fadd_rn(zv.z, __fsub_rn(qv.z, zv.z));
    o.w = __fadd_rn(zv.w, __fsub_rn(qv.w, zv.w));
    *(float4*)(out0 + (size_t)row * D_DIM + d) = o;
    float dx = qv.x - zv.x, dy = qv.y - zv.y, dz = qv.z - zv.z, dw = qv.w - zv.w;
    float s = dx * dx + dy * dy + dz * dz + dw * dw;
#pragma unroll
    for (int off = 32; off; off >>= 1) s += __shfl_down(s, off, 64);
    __shared__ float part[2];
    if ((t & 63) == 0) part[t >> 6] = s;
    __syncthreads();
    if (t == 0) atomicAdd(loss_acc, part[0] + part[1]);
}

// ---------------- block0: prefix over counts; block1: cs-sum + loss ----------------
__global__ void prefix_sum_kernel(const int* __restrict__ cnt, int* __restrict__ offs,
                                  const float* __restrict__ cs, float* __restrict__ s_in,
                                  const float* __restrict__ loss_acc, float* __restrict__ out1) {
    if (blockIdx.x == 0) {
        __shared__ int sums[1024];
        int t = threadIdx.x;
        int base = t * 8;
        int loc[8]; int s = 0;
#pragma unroll
        for (int i = 0; i < 8; i++) { loc[i] = s; s += cnt[base + i]; }
        sums[t] = s;
        __syncthreads();
        for (int off = 1; off < 1024; off <<= 1) {
            int v = (t >= off) ? sums[t - off] : 0;
            __syncthreads();
            sums[t] += v;
            __syncthreads();
        }
        int excl = sums[t] - s;
#pragma unroll
        for (int i = 0; i < 8; i++) offs[base + i] = excl + loc[i];
    } else {
        int t = threadIdx.x;
        __shared__ float part[4];
        if (t < 256) {
            float s = 0.f;
            for (int i = t; i < K_CODES; i += 256) s += cs[i];
#pragma unroll
            for (int off = 32; off; off >>= 1) s += __shfl_down(s, off, 64);
            if ((t & 63) == 0) part[t >> 6] = s;
        }
        __syncthreads();
        if (t == 0) {
            s_in[0] = part[0] + part[1] + part[2] + part[3];
            out1[0] = COMMIT * loss_acc[0] / (float)(N_ROWS * D_DIM);
        }
    }
}

__global__ void fill_kernel(const int* __restrict__ idx, int* __restrict__ offs,
                            int* __restrict__ rowlist) {
    int row = blockIdx.x * 256 + threadIdx.x;
    int k = idx[row];
    int pos = atomicAdd(&offs[k], 1);
    rowlist[pos] = row;
}

__global__ void cluster_kernel(const float* __restrict__ z, const float* __restrict__ in_cs,
                               const float* __restrict__ in_es, const int* __restrict__ cnt,
                               const int* __restrict__ offs_end, const int* __restrict__ rowlist,
                               const float* __restrict__ s_in,
                               float* __restrict__ out3, float* __restrict__ out4,
                               float* __restrict__ out5) {
    int k = blockIdx.x;
    int t = threadIdx.x;  // 128
    int c = cnt[k];
    int end = offs_end[k];
    int start = end - c;
    int d = t * 4;
    float ax = 0.f, ay = 0.f, az = 0.f, aw = 0.f;
    for (int i = 0; i < c; i++) {
        int row = rowlist[start + i];
        float4 zv = *(const float4*)(z + (size_t)row * D_DIM + d);
        ax += zv.x; ay += zv.y; az += zv.z; aw += zv.w;
    }
    float ema_cs = DECAYF * in_cs[k] + OMDF * (float)c;
    float n = DECAYF * s_in[0] + OMDF * (float)N_ROWS;
    float smoothed = (ema_cs + EPSV) / (n + (float)K_CODES * EPSV) * n;
    float4 esv = *(const float4*)(in_es + (size_t)k * D_DIM + d);
    float4 ema;
    ema.x = DECAYF * esv.x + OMDF * ax;
    ema.y = DECAYF * esv.y + OMDF * ay;
    ema.z = DECAYF * esv.z + OMDF * az;
    ema.w = DECAYF * esv.w + OMDF * aw;
    *(float4*)(out5 + (size_t)k * D_DIM + d) = ema;
    float4 emb;
    emb.x = ema.x / smoothed;
    emb.y = ema.y / smoothed;
    emb.z = ema.z / smoothed;
    emb.w = ema.w / smoothed;
    *(float4*)(out3 + (size_t)k * D_DIM + d) = emb;
    if (t == 0) out4[k] = ema_cs;
}

extern "C" void kernel_launch(void* const* d_in, const int* in_sizes, int n_in,
                              void* d_out, int out_size, void* d_ws, size_t ws_size,
                              hipStream_t stream) {
    const float* z     = (const float*)d_in[0];
    const float* E     = (const float*)d_in[1];
    const float* in_cs = (const float*)d_in[2];
    const float* in_es = (const float*)d_in[3];

    float* out  = (float*)d_out;
    float* out0 = out + OUT0_OFF;
    float* out1 = out + OUT1_OFF;
    float* out2 = out + OUT2_OFF;
    float* out3 = out + OUT3_OFF;
    float* out4 = out + OUT4_OFF;
    float* out5 = out + OUT5_OFF;

    // packed planes stashed in output regions (consumed before those outputs write)
    u16* zpack = (u16*)out0;                                 // 32 MB
    u16* epack = (u16*)(out + OUT3_OFF + 3);                 // 16 MB (+12B spill into out4, rewritten)
    // scratch in out5 region (16.8 MB), all consumed before cluster writes out5:
    float* pv2    = out5;                                    // 2 MB exact per-(cb,row)
    int*   pi2    = (int*)(out5 + 524288);                   // 2 MB
    float* pvest  = out5 + 2 * 524288;                       // 2 MB est per-(cb,row)
    int*   cbrows = (int*)(out5 + 3 * 524288);               // 2 MB flagged row lists

    char* ws = (char*)d_ws;
    float* e2      = (float*)(ws);                           // 32 KB
    float* z2      = (float*)(ws + 32 * 1024);               // 64 KB
    int*   idxb    = (int*)  (ws + 96 * 1024);               // 64 KB
    int*   cnt     = (int*)  (ws + 160 * 1024);              // 32 KB
    int*   offs    = (int*)  (ws + 192 * 1024);              // 32 KB
    int*   rowlist = (int*)  (ws + 224 * 1024);              // 64 KB
    float* loss    = (float*)(ws + 288 * 1024);              // 4 B
    float* s_in    = loss + 1;                               // 4 B
    unsigned* mehbits = (unsigned*)(ws + 288 * 1024 + 8);    // 4 B
    unsigned* melbits = mehbits + 1;                         // 4 B
    int*   cnt2    = (int*)  (ws + 288 * 1024 + 16);         // 128 B
    float* nzh2    = (float*)(ws + 320 * 1024);              // 64 KB
    float* nzl2    = (float*)(ws + 384 * 1024);              // 64 KB

    hipMemsetAsync(mehbits, 0, 136, stream);                 // MEH/MEL/cnt2
    hipMemsetAsync(pv2, 0x7F, 2 * 1024 * 1024, stream);      // +inf-ish sentinel

    prep_kernel<<<7681, 256, 0, stream>>>(z, E, zpack, epack, z2, e2,
                                          nzh2, nzl2, mehbits, melbits, cnt, loss);
    est_mfma_kernel<<<NRB * NCB, 512, 0, stream>>>(zpack, epack, e2, z2, pvest);
    flag_kernel<<<N_ROWS / 256, 256, 0, stream>>>(pvest, nzh2, nzl2, mehbits, melbits,
                                                  cnt2, cbrows);
    refine_mfma_kernel<<<32 * 128, 512, 0, stream>>>(zpack, epack, e2, z2,
                                                     cnt2, cbrows, pv2, pi2);
    combine_gather_kernel<<<N_ROWS, 128, 0, stream>>>(pv2, pi2, z, E, idxb, out2, cnt,
                                                      out0, loss);
    prefix_sum_kernel<<<2, 1024, 0, stream>>>(cnt, offs, in_cs, s_in, loss, out1);
    fill_kernel<<<N_ROWS / 256, 256, 0, stream>>>(idxb, offs, rowlist);
    cluster_kernel<<<K_CODES, 128, 0, stream>>>(z, in_cs, in_es, cnt, offs, rowlist,
                                                s_in, out3, out4, out5);
}